// Round 10
// baseline (24828.624 us; speedup 1.0000x reference)
//
#include <hip/hip_runtime.h>
#include <hip/hip_bf16.h>

typedef float  f32x4 __attribute__((ext_vector_type(4)));
typedef float  f32x2 __attribute__((ext_vector_type(2)));
typedef int    i32x4 __attribute__((ext_vector_type(4)));
typedef int    i32x6 __attribute__((ext_vector_type(6)));
typedef int    i32x8 __attribute__((ext_vector_type(8)));

#define NB   8
#define LSEQ 2048
#define DDIM 512
#define KC   16

__device__ __forceinline__ float rcp_(float x){ return __builtin_amdgcn_rcpf(x); }
__device__ __forceinline__ float ex2_(float x){ return __builtin_amdgcn_exp2f(x); }
__device__ __forceinline__ float clamp60(float x){ return fminf(fmaxf(x, -60.f), 60.f); }
__device__ __forceinline__ float blo(unsigned u){ return __uint_as_float(u<<16); }
__device__ __forceinline__ float bhi(unsigned u){ return __uint_as_float(u & 0xffff0000u); }
__device__ __forceinline__ unsigned pk2(float a, float b){
    __hip_bfloat16 x=__float2bfloat16(a), y=__float2bfloat16(b);
    return (unsigned)*(unsigned short*)&x | ((unsigned)*(unsigned short*)&y<<16);
}

#define GLDS(gp, lp) __builtin_amdgcn_global_load_lds(                      \
    (__attribute__((address_space(1))) const void*)(gp),                   \
    (__attribute__((address_space(3))) void*)(lp), 16, 0, 0)

// ================= prep: casts + bias + convw + poswin + counter zero =================
// wihbf/bias2 gate-interleaved: out row (lp, p*4+q) = src row (lp, q*256+p).
__global__ __launch_bounds__(256) void k_prep(const float* __restrict__ hidden, __hip_bfloat16* __restrict__ hbf,
                                              const float* __restrict__ Wih, __hip_bfloat16* __restrict__ wihbf,
                                              const float* __restrict__ bih, const float* __restrict__ bhh,
                                              float* __restrict__ bias2,
                                              const float* __restrict__ convw, __hip_bfloat16* __restrict__ wtc,
                                              const int* __restrict__ aa, int* __restrict__ pos,
                                              float* __restrict__ cm, float* __restrict__ win,
                                              int* __restrict__ cnt){
    int bid = blockIdx.x, tid = threadIdx.x;
    if(bid < 4096){                                  // cast hidden -> bf16 (x8)
        size_t i = (size_t)bid*256 + tid;
        const f32x4* s = (const f32x4*)(hidden + i*8);
        f32x4 v0 = s[0], v1 = s[1];
        i32x4 o; o.x = pk2(v0.x,v0.y); o.y = pk2(v0.z,v0.w);
                 o.z = pk2(v1.x,v1.y); o.w = pk2(v1.z,v1.w);
        ((i32x4*)hbf)[i] = o;
    } else if(bid < 5120){                           // cast Wih -> bf16, gate-interleaved rows
        size_t o = ((size_t)(bid-4096)*256 + tid) * 8;
        int Rp  = (int)(o >> 9);
        int col = (int)(o & 511);
        int lp  = Rp >> 10;
        int base= Rp & 1023;
        int p = base >> 2, q = base & 3;
        int Rs = (lp<<10) + (q<<8) + p;
        const f32x4* s = (const f32x4*)(Wih + ((size_t)Rs << 9) + col);
        f32x4 v0 = s[0], v1 = s[1];
        i32x4 oo; oo.x = pk2(v0.x,v0.y); oo.y = pk2(v0.z,v0.w);
                  oo.z = pk2(v1.x,v1.y); oo.w = pk2(v1.z,v1.w);
        ((i32x4*)wihbf)[o>>3] = oo;
    } else if(bid < 5136){                           // bias2 = bih + bhh, gate-interleaved
        int i = (bid-5120)*256 + tid;
        int l = i >> 11, b2 = i & 2047;
        int dir = b2 >> 10, b = b2 & 1023;
        int p = b >> 2, q = b & 3;
        int src = ((l*2+dir)<<10) + (q<<8) + p;
        bias2[i] = bih[src] + bhh[src];
    } else if(bid < 6160){                           // conv_w transpose -> wt[tap][co][ci]
        int idx = (bid-5136)*256 + tid;
        #pragma unroll
        for(int tap=0; tap<11; ++tap)
            wtc[(size_t)tap*262144 + idx] = __float2bfloat16(convw[(size_t)idx*11 + tap]);
    } else if(bid < 6168){                           // poswin
        int b = bid - 6160;
        __shared__ unsigned char fl[LSEQ];
        for(int t=tid; t<LSEQ; t+=256) fl[t] = (aa[b*LSEQ+t]==4) ? 1 : 0;
        __syncthreads();
        if(tid==0){
            int c=0;
            for(int t=0; t<LSEQ && c<KC; ++t) if(fl[t]) pos[b*KC + c++] = t;
            for(; c<KC; ++c) pos[b*KC+c]=0;
        }
        for(int t=tid; t<LSEQ; t+=256){
            cm[b*LSEQ+t] = fl[t] ? 1.f : 0.f;
            int lo = t-5 < 0 ? 0 : t-5;
            int hi = t+5 > LSEQ-1 ? LSEQ-1 : t+5;
            float wv = 0.f;
            for(int u=lo; u<=hi; ++u) if(fl[u]) wv = 1.f;
            win[b*LSEQ+t] = wv;
        }
    } else {                                          // zero ready-counters (both layers)
        if(tid < 256) cnt[tid] = 0;
    }
}

// ================= GEMM guest: 128x128 tile, ready-counter release =================
__device__ __forceinline__ void gemm_body(char* smem, const __hip_bfloat16* __restrict__ A,
        const __hip_bfloat16* __restrict__ Bw, const float* __restrict__ bias,
        __hip_bfloat16* __restrict__ C, int* __restrict__ cnt, int g){
    const int KD = 512, N = 2048;
    int nt = g & 15;
    int j  = g >> 4;                       // [0,128)
    int kpos = j >> 3, bat = j & 7;
    int mt = bat*16 + ((kpos&1) ? (15 - (kpos>>1)) : (kpos>>1));
    __hip_bfloat16 (*As)[32] = (__hip_bfloat16(*)[32])smem;
    __hip_bfloat16 (*Bs)[32] = (__hip_bfloat16(*)[32])(smem + 8192);
    int tid = threadIdx.x, w = tid>>6, lane = tid&63, lo = lane&15, hi = lane>>4;
    int wm = w>>1, wn = w&1;
    f32x4 acc[2][4];
    #pragma unroll
    for(int s=0;s<2;s++){
        #pragma unroll
        for(int t2=0;t2<4;t2++) acc[s][t2] = (f32x4){0.f,0.f,0.f,0.f};
    }
    int lr = tid>>2, lc = (tid&3)*8;
    const __hip_bfloat16* Ab = A  + (size_t)(mt*128)*KD;
    const __hip_bfloat16* Bb = Bw + (size_t)(nt*128)*KD;
    for(int kk=0; kk<KD; kk+=32){
        __builtin_amdgcn_s_barrier();
        GLDS(Ab + (size_t)lr*KD + kk + lc, &As[lr][lc]);
        GLDS(Bb + (size_t)lr*KD + kk + lc, &Bs[lr][lc]);
        asm volatile("s_waitcnt vmcnt(0)" ::: "memory");
        __builtin_amdgcn_s_barrier();
        i32x4 av[2], bv[4];
        #pragma unroll
        for(int s=0;s<2;s++) av[s] = *(const i32x4*)(&As[wm*32+s*16+lo][hi*8]);
        #pragma unroll
        for(int t2=0;t2<4;t2++) bv[t2] = *(const i32x4*)(&Bs[wn*64+t2*16+lo][hi*8]);
        asm volatile("s_nop 1" ::);
        #pragma unroll
        for(int s=0;s<2;s++){
            #pragma unroll
            for(int t2=0;t2<4;t2++)
                asm volatile("v_mfma_f32_16x16x32_bf16 %0, %1, %2, %0" : "+v"(acc[s][t2]) : "v"(av[s]), "v"(bv[t2]));
        }
    }
    asm volatile("s_nop 7\n\ts_nop 7" ::);
    #pragma unroll
    for(int t2=0;t2<4;t2++){
        int n = nt*128 + wn*64 + t2*16 + lo;
        float bn = bias[n];
        #pragma unroll
        for(int s=0;s<2;s++){
            #pragma unroll
            for(int rr=0;rr<4;rr++){
                int m = mt*128 + wm*32 + s*16 + hi*4 + rr;
                C[(size_t)m*N + n] = __float2bfloat16(acc[s][t2][rr] + bn);
            }
        }
    }
    asm volatile("s_waitcnt vmcnt(0)" ::: "memory");
    __syncthreads();
    if(tid==0)
        __hip_atomic_fetch_add(cnt + mt, 1, __ATOMIC_RELEASE, __HIP_MEMORY_SCOPE_AGENT);
}

// ================= LSTM recurrence body =================
// One 512-thr WG per (batch,dir). Whh in fp6-e2m3 (per-gate-row pow2 scale) held in
// AGPRs; A = h in fp8. v_mfma_f32_16x16x128_f8f6f4 cbsz:0 blgp:2 runs at the fp4 rate
// (~1.55x fp8). Row descale folded into epilogue. Gx direct register ring; 1 barrier/step.
__device__ __forceinline__ void recur_body(char* smem, const float* __restrict__ Whh,
        const __hip_bfloat16* __restrict__ Gx, __hip_bfloat16* __restrict__ Hout,
        const int* __restrict__ cnt, int layer, int bat, int dir){
    unsigned char (*hb)[256] = (unsigned char(*)[256])smem;   // 2 x 256 (h fp8)
    const int tid = threadIdx.x, w = tid>>6, lane = tid&63, lo = lane&15, hi = lane>>4;
    for(int i=tid; i<128; i+=512) ((int*)smem)[i] = 0;

    // Whh -> fp6 e2m3 fragments in AGPRs. Fragment i=q*2+s covers gate row
    // j = q*256 + w*32 + s*16 + lo; per-row pow2 scale puts rowmax in [4,8).
    i32x6 bf6[8][2];
    float ds[4];
    const float* wbase = Whh + ((size_t)(layer*2 + dir)*1024)*256;
    #pragma unroll
    for(int q=0;q<4;q++){
        #pragma unroll
        for(int s=0;s<2;s++){
            int j = q*256 + w*32 + s*16 + lo;
            const float* wr = wbase + (size_t)j*256;
            // pass 1: row max (this lane's 64 vals, then reduce across hi-groups)
            float mx = 0.f;
            #pragma unroll
            for(int c=0;c<2;c++){
                #pragma unroll
                for(int u=0; u<8; ++u){
                    f32x4 wv = *(const f32x4*)(wr + c*128 + hi*32 + u*4);
                    mx = fmaxf(mx, fmaxf(fmaxf(fabsf(wv.x),fabsf(wv.y)), fmaxf(fabsf(wv.z),fabsf(wv.w))));
                }
            }
            mx = fmaxf(mx, __shfl_xor(mx, 16));
            mx = fmaxf(mx, __shfl_xor(mx, 32));
            int ex; frexpf(mx, &ex);                 // mx = f*2^ex, f in [.5,1)
            float srow = ldexpf(1.f, 3-ex);          // mx*srow in [4,8)
            if(s == (hi&1)) ds[q] = ldexpf(1.f, ex-3);
            // pass 2: quantize to e2m3 and pack 32x6 bits -> 6 dwords
            #pragma unroll
            for(int c=0;c<2;c++){
                i32x6 v;
                #pragma unroll
                for(int z=0;z<6;z++) v[z] = 0;
                #pragma unroll
                for(int u=0; u<8; ++u){
                    f32x4 wv = *(const f32x4*)(wr + c*128 + hi*32 + u*4);
                    #pragma unroll
                    for(int x=0;x<4;x++){
                        float wl = (x==0)?wv.x:((x==1)?wv.y:((x==2)?wv.z:wv.w));
                        unsigned sg = (__float_as_uint(wl)>>31) & 1u;
                        float a = fabsf(wl) * srow;
                        int e, m;
                        if(a < 2.f){
                            int t = (int)rintf(a*8.f);
                            if(t < 8){ e=0; m=t; } else if(t < 16){ e=1; m=t-8; } else { e=2; m=0; }
                        } else if(a < 4.f){
                            int t = (int)rintf(a*4.f);
                            if(t < 16){ e=2; m=t-8; } else { e=3; m=0; }
                        } else {
                            int t = (int)rintf(a*2.f);
                            if(t > 15) t = 15;
                            e=3; m=t-8;
                        }
                        unsigned code = (sg<<5) | ((unsigned)e<<3) | (unsigned)m;
                        int bitp = (u*4+x)*6, wd = bitp>>5, bt = bitp&31;
                        v[wd] |= (int)(code << bt);
                        if(bt > 26) v[wd+1] |= (int)(code >> (32-bt));
                    }
                }
                bf6[q*2+s][c] = v;
            }
        }
    }
    const int pm = w*32 + ((hi&1)<<4) + lo;
    float cst = 0.f;
    const __hip_bfloat16* gxb = Gx + (size_t)bat*LSEQ*2048 + dir*1024;
    const int cbase = bat*16;
    int mtr = -1;

    uint2 gc, gn;   // gx(t), gx(t+1) in registers
    {   // prologue: acquire first tile, load gx(0), gx(1)
        int tok0 = dir ? (LSEQ-1) : 0;
        int tok1 = dir ? (LSEQ-2) : 1;
        int mtn = cbase + (tok0>>7);
        if(lane==0){
            while(__hip_atomic_load(cnt+mtn, __ATOMIC_ACQUIRE, __HIP_MEMORY_SCOPE_AGENT) < 16)
                __builtin_amdgcn_s_sleep(2);
        }
        mtr = mtn;
        gc = *(const uint2*)(gxb + (size_t)tok0*2048 + pm*4);
        gn = *(const uint2*)(gxb + (size_t)tok1*2048 + pm*4);
    }
    asm volatile("s_waitcnt lgkmcnt(0)" ::: "memory");
    __builtin_amdgcn_s_barrier();
    __builtin_amdgcn_sched_barrier(0);

    for(int t=0; t<LSEQ; ++t){
        const int tt = dir ? (LSEQ-1-t) : t;
        const int hcur = t&1, hnxt = hcur^1;
        // prefetch gx(t+2) into register (poll ready-counter at tile crossings)
        uint2 gf2;
        {
            int tp = (t+2 < LSEQ) ? (t+2) : (LSEQ-1);
            int tok = dir ? (LSEQ-1-tp) : tp;
            int mtn = cbase + (tok>>7);
            if(mtn != mtr){
                if(lane==0){
                    while(__hip_atomic_load(cnt+mtn, __ATOMIC_ACQUIRE, __HIP_MEMORY_SCOPE_AGENT) < 16)
                        __builtin_amdgcn_s_sleep(2);
                }
                mtr = mtn;
            }
            gf2 = *(const uint2*)(gxb + (size_t)tok*2048 + pm*4);
        }
        // A: broadcast h (fp8) slice for this lane's k-group (conflict-free)
        i32x8 af[2];
        #pragma unroll
        for(int c=0;c<2;c++){
            i32x4 v0 = *(const i32x4*)(&hb[hcur][c*128 + hi*32]);
            i32x4 v1 = *(const i32x4*)(&hb[hcur][c*128 + hi*32 + 16]);
            af[c] = __builtin_shufflevector(v0, v1, 0,1,2,3,4,5,6,7);
        }
        // 16 independent MFMAs: A fp8 (cbsz:0), B fp6 (blgp:2) at fp4 rate
        f32x4 aa[8], ab[8];
        #pragma unroll
        for(int i=0;i<8;i++){ aa[i] = (f32x4){0.f,0.f,0.f,0.f}; ab[i] = (f32x4){0.f,0.f,0.f,0.f}; }
        asm volatile("s_nop 1" ::);
        #pragma unroll
        for(int i=0;i<8;i++)
            asm volatile("v_mfma_f32_16x16x128_f8f6f4 %0, %1, %2, %0 cbsz:0 blgp:2"
                         : "+v"(aa[i]) : "v"(af[0]), "a"(bf6[i][0]));
        #pragma unroll
        for(int i=0;i<8;i++)
            asm volatile("v_mfma_f32_16x16x128_f8f6f4 %0, %1, %2, %0 cbsz:0 blgp:2"
                         : "+v"(ab[i]) : "v"(af[1]), "a"(bf6[i][1]));
        asm volatile("s_nop 7\n\ts_nop 7" ::);
        {   // epilogue (gates in registers; row descale; gx from register ring)
            float aI = ((hi&1) ? (aa[1][0]+ab[1][0]) : (aa[0][0]+ab[0][0])) * ds[0];
            float aF = ((hi&1) ? (aa[3][0]+ab[3][0]) : (aa[2][0]+ab[2][0])) * ds[1];
            float aG = ((hi&1) ? (aa[5][0]+ab[5][0]) : (aa[4][0]+ab[4][0])) * ds[2];
            float aO = ((hi&1) ? (aa[7][0]+ab[7][0]) : (aa[6][0]+ab[6][0])) * ds[3];
            float gi = aI + blo(gc.x);
            float gf = aF + bhi(gc.x);
            float gg = aG + blo(gc.y);
            float go = aO + bhi(gc.y);
            float sf = rcp_(1.f + ex2_(gf * -1.44269504f));
            float ag = ex2_(clamp60(gg * 2.88539008f));
            float bi = ex2_(clamp60(gi * -1.44269504f));
            float it = (ag - 1.f) * rcp_((1.f + bi) * (ag + 1.f));
            float c  = sf*cst + it;
            cst = c;
            float ac = ex2_(clamp60(c * 2.88539008f));
            float bo = ex2_(clamp60(go * -1.44269504f));
            float h  = (ac - 1.f) * rcp_((1.f + bo) * (ac + 1.f));
            if(hi < 2){
                int pk = __builtin_amdgcn_cvt_pk_fp8_f32(h, h, 0, false);
                hb[hnxt][pm] = (unsigned char)(pk & 0xff);
                Hout[((size_t)bat*LSEQ + tt)*512 + dir*256 + pm] = __float2bfloat16(h);
            }
        }
        // publish hb only (gx register-tracked, stores free-run)
        asm volatile("s_waitcnt lgkmcnt(0)" ::: "memory");
        __builtin_amdgcn_s_barrier();
        __builtin_amdgcn_sched_barrier(0);
        gc = gn; gn = gf2;
    }
}

// ================= bilinear body =================
__device__ __forceinline__ void bilinear_body(char* smem, const float* __restrict__ hidden,
        const int* __restrict__ pos, const float* __restrict__ Wb, const float* __restrict__ bb,
        float* __restrict__ pf, int idx){
    int c = idx & 127, b = idx >> 7;
    float (*fl)[516] = (float(*)[516])smem;
    float (*tl)[516] = (float(*)[516])(smem + 33024);
    int tid = threadIdx.x;
    for(int i=tid; i<2048; i+=512){
        int k = i>>7, d = (i&127)*4;
        int p = pos[b*KC + k];
        f32x4 v = *(const f32x4*)(hidden + ((size_t)b*LSEQ + p)*DDIM + d);
        fl[k][d]=v.x; fl[k][d+1]=v.y; fl[k][d+2]=v.z; fl[k][d+3]=v.w;
    }
    __syncthreads();
    int e = tid;
    float acc[16];
    #pragma unroll
    for(int k=0;k<16;k++) acc[k]=0.f;
    const float* wc = Wb + (size_t)c*512*512;
    for(int d=0; d<512; ++d){
        float wv = wc[(size_t)d*512 + e];
        #pragma unroll
        for(int k=0;k<16;k++) acc[k] += fl[k][d]*wv;
    }
    #pragma unroll
    for(int k=0;k<16;k++) tl[k][e] = acc[k];
    __syncthreads();
    if(tid < 256){
        int kq = tid>>4, mq = tid&15;
        const f32x4* tp = (const f32x4*)&tl[kq][0];
        const f32x4* fp = (const f32x4*)&fl[mq][0];
        float s = 0.f;
        #pragma unroll 8
        for(int e2=0;e2<128;e2++){ f32x4 a=tp[e2], v=fp[e2]; s += a.x*v.x + a.y*v.y + a.z*v.z + a.w*v.w; }
        pf[(((size_t)b*16+kq)*16+mq)*128 + c] = s + bb[c];
    }
}

// ================= cls + greedy body =================
__device__ __forceinline__ void clsgreedy_body(char* smem, const float* __restrict__ pf,
        const float* __restrict__ w1, const float* __restrict__ b1,
        const float* __restrict__ w2, const float* __restrict__ b2,
        const int* __restrict__ pos, float* __restrict__ prob, float* __restrict__ sel, int b){
    float (*sw1)[128] = (float(*)[128])smem;
    float* sw2 = (float*)(smem + 32768);
    float* sb1 = sw2 + 64;
    float* sp  = sb1 + 64;
    unsigned char* si = (unsigned char*)(sp + 120);
    unsigned char* sj = si + 120;
    int tid = threadIdx.x;
    for(int i=tid; i<8192; i+=512) sw1[i>>7][i&127] = w1[i];
    if(tid<64){ sw2[tid]=w2[tid]; sb1[tid]=b1[tid]; }
    if(tid==0){
        int idx=0;
        for(int i=0;i<16;i++) for(int j=i+1;j<16;j++){ si[idx]=(unsigned char)i; sj[idx]=(unsigned char)j; idx++; }
    }
    if(tid<256) sel[b*256+tid] = 0.f;
    __syncthreads();
    if(tid < 256){
        int k = tid>>4, m = tid&15;
        const f32x4* pp = (const f32x4*)(pf + (((size_t)b*16+k)*16+m)*128);
        f32x4 pr[32];
        #pragma unroll
        for(int i=0;i<32;i++) pr[i] = pp[i];
        float lg = b2[0];
        for(int n=0;n<64;n++){
            const f32x4* wr = (const f32x4*)&sw1[n][0];
            float a = sb1[n];
            #pragma unroll
            for(int i=0;i<32;i++){ f32x4 wv = wr[i]; a += pr[i].x*wv.x + pr[i].y*wv.y + pr[i].z*wv.z + pr[i].w*wv.w; }
            a = fmaxf(a, 0.f);
            lg += a*sw2[n];
        }
        float p = rcp_(1.f + ex2_(lg * -1.44269504f));
        int dk = pos[b*16+k]-pos[b*16+m]; if(dk<0) dk=-dk;
        if(dk<2) p *= 0.1f;
        prob[b*256 + k*16 + m] = p;
        if(k < m) sp[k*(31-k)/2 + (m-k-1)] = p;
    }
    __syncthreads();
    if(tid==0){
        bool done[120]; bool used[16];
        for(int i=0;i<120;i++) done[i]=false;
        for(int i=0;i<16;i++)  used[i]=false;
        for(int it=0; it<120; ++it){
            int bi=-1; float bp=-1e30f;
            for(int q=0;q<120;q++) if(!done[q] && sp[q]>bp){ bp=sp[q]; bi=q; }
            done[bi]=true;
            if(bp>0.5f && !used[si[bi]] && !used[sj[bi]]){
                used[si[bi]]=true; used[sj[bi]]=true;
                sel[b*256 + si[bi]*16 + sj[bi]] = 1.f;
            }
        }
    }
}

// ================= fused launches =================
__global__ __launch_bounds__(512) void k_fused1(const float* __restrict__ Whh, __hip_bfloat16* __restrict__ Gx,
        __hip_bfloat16* __restrict__ Hout, int* __restrict__ cnt,
        const __hip_bfloat16* __restrict__ hbf, const __hip_bfloat16* __restrict__ wihbf,
        const float* __restrict__ bias2,
        const float* __restrict__ hidden, const int* __restrict__ pos,
        const float* __restrict__ Wbil, const float* __restrict__ bbil, float* __restrict__ pf){
    __shared__ __attribute__((aligned(16))) char smem[98304];
    int bid = blockIdx.x;
    if(bid < 16){
        recur_body(smem, Whh, Gx, Hout, cnt, 0, bid>>1, bid&1);
    } else if(bid < 16 + 2048){
        gemm_body(smem, hbf, wihbf, bias2, Gx, cnt, bid - 16);
    } else {
        bilinear_body(smem, hidden, pos, Wbil, bbil, pf, bid - 2064);
    }
}

__global__ __launch_bounds__(512) void k_fused2(const float* __restrict__ Whh, __hip_bfloat16* __restrict__ Gx,
        __hip_bfloat16* __restrict__ Hout, int* __restrict__ cnt,
        const __hip_bfloat16* __restrict__ out1, const __hip_bfloat16* __restrict__ wihbf,
        const float* __restrict__ bias2,
        const float* __restrict__ pf, const float* __restrict__ w1, const float* __restrict__ b1,
        const float* __restrict__ w2, const float* __restrict__ b2, const int* __restrict__ pos,
        float* __restrict__ prob, float* __restrict__ sel){
    __shared__ __attribute__((aligned(16))) char smem[98304];
    int bid = blockIdx.x;
    if(bid < 16){
        recur_body(smem, Whh, Gx, Hout, cnt, 1, bid>>1, bid&1);
    } else if(bid < 16 + 2048){
        gemm_body(smem, out1, wihbf + (size_t)2048*512, bias2 + 2048, Gx, cnt, bid - 16);
    } else {
        clsgreedy_body(smem, pf, w1, b1, w2, b2, pos, prob, sel, bid - 2064);
    }
}

// ================= conv (ce computed in staging) + final fusion =================
// co split in halves; XCD-parity mapping keeps one 2.88MB wt-half L2-resident per XCD.
__global__ __launch_bounds__(256) void k_convce(const float* __restrict__ hs, const __hip_bfloat16* __restrict__ opt,
        const float* __restrict__ win, const float* __restrict__ cm, const float* __restrict__ dsb,
        const __hip_bfloat16* __restrict__ wt, const float* __restrict__ convb, float* __restrict__ outp){
    int xcd = blockIdx.x & 7;          // MI355X round-robin dispatch heuristic (perf-only)
    int j   = blockIdx.x >> 3;         // [0,64)
    int coH = xcd & 1;
    int tix = (xcd >> 1) * 64 + j;     // [0,256)
    int mt  = tix >> 3, b = tix & 7;
    __shared__ __hip_bfloat16 S[74][520];
    int tid = threadIdx.x;
    for(int i=tid; i<74*64; i+=256){
        int rq = i>>6, cc = (i&63)*8;
        int tok = mt*64 - 5 + rq;
        i32x4 o = (i32x4){0,0,0,0};
        if(tok>=0 && tok<LSEQ){
            size_t base = ((size_t)b*LSEQ + tok)*512 + cc;
            float wv = win[b*LSEQ+tok]*0.4f, cv = cm[b*LSEQ+tok];
            f32x4 h0 = *(const f32x4*)(hs + base);
            f32x4 h1 = *(const f32x4*)(hs + base + 4);
            unsigned long long u0 = *(const unsigned long long*)(opt + base);
            unsigned long long u1 = *(const unsigned long long*)(opt + base + 4);
            f32x4 d0 = *(const f32x4*)(dsb + cc);
            f32x4 d1 = *(const f32x4*)(dsb + cc + 4);
            float c0 = h0.x + wv*__uint_as_float((unsigned)(u0      & 0xffffull)<<16) + d0.x*cv;
            float c1 = h0.y + wv*__uint_as_float((unsigned)((u0>>16)& 0xffffull)<<16) + d0.y*cv;
            float c2 = h0.z + wv*__uint_as_float((unsigned)((u0>>32)& 0xffffull)<<16) + d0.z*cv;
            float c3 = h0.w + wv*__uint_as_float((unsigned)((u0>>48)& 0xffffull)<<16) + d0.w*cv;
            float c4 = h1.x + wv*__uint_as_float((unsigned)(u1      & 0xffffull)<<16) + d1.x*cv;
            float c5 = h1.y + wv*__uint_as_float((unsigned)((u1>>16)& 0xffffull)<<16) + d1.y*cv;
            float c6 = h1.z + wv*__uint_as_float((unsigned)((u1>>32)& 0xffffull)<<16) + d1.z*cv;
            float c7 = h1.w + wv*__uint_as_float((unsigned)((u1>>48)& 0xffffull)<<16) + d1.w*cv;
            o.x = pk2(c0,c1); o.y = pk2(c2,c3); o.z = pk2(c4,c5); o.w = pk2(c6,c7);
        }
        *(i32x4*)(&S[rq][cc]) = o;
    }
    __syncthreads();
    int w = tid>>6, lane = tid&63, lo = lane&15, hi = lane>>4;
    f32x4 acc[4][4];                    // [ms][s] — co slice = coH*256 + w*64 + s*16 + lo
    #pragma unroll
    for(int ms=0;ms<4;ms++){
        #pragma unroll
        for(int s=0;s<4;s++) acc[ms][s] = (f32x4){0.f,0.f,0.f,0.f};
    }
    asm volatile("s_nop 1" ::);
    for(int tap=0; tap<11; ++tap){
        const __hip_bfloat16* wtp = wt + (size_t)tap*262144 + (size_t)(coH*256 + w*64)*512;
        for(int kk=0; kk<512; kk+=32){
            i32x4 a[4];
            #pragma unroll
            for(int ms=0;ms<4;ms++) a[ms] = *(const i32x4*)(&S[ms*16 + lo + tap][kk + hi*8]);
            #pragma unroll
            for(int s=0;s<4;s++){
                i32x4 bq = *(const i32x4*)(wtp + (size_t)(s*16 + lo)*512 + kk + hi*8);
                #pragma unroll
                for(int ms=0;ms<4;ms++)
                    asm volatile("v_mfma_f32_16x16x32_bf16 %0, %1, %2, %0" : "+v"(acc[ms][s]) : "v"(a[ms]), "v"(bq));
            }
        }
    }
    asm volatile("s_nop 7\n\ts_nop 7" ::);
    #pragma unroll
    for(int s=0;s<4;s++){
        int co = coH*256 + w*64 + s*16 + lo;
        float cb = convb[co];
        #pragma unroll
        for(int ms=0;ms<4;ms++){
            #pragma unroll
            for(int rr=0; rr<4; ++rr){
                int row = ms*16 + hi*4 + rr;
                int tok = mt*64 + row;
                size_t gi = ((size_t)b*LSEQ + tok)*512 + co;
                float h   = hs[gi];
                float cef = __bfloat162float(S[row + 5][co]);
                outp[gi] = 0.5f*h + 0.3f*cef + 0.2f*(acc[ms][s][rr] + cb);
            }
        }
    }
}

// ================= launch =================
extern "C" void kernel_launch(void* const* d_in, const int* in_sizes, int n_in,
                              void* d_out, int out_size, void* d_ws, size_t ws_size,
                              hipStream_t stream)
{
    (void)in_sizes; (void)n_in; (void)out_size; (void)ws_size;
    const float* hidden = (const float*)d_in[0];
    const int*   aa     = (const int*)d_in[1];
    const float* Wbil   = (const float*)d_in[2];
    const float* bbil   = (const float*)d_in[3];
    const float* w1     = (const float*)d_in[4];
    const float* b1     = (const float*)d_in[5];
    const float* w2     = (const float*)d_in[6];
    const float* b2     = (const float*)d_in[7];
    const float* Wih    = (const float*)d_in[8];
    const float* Whh    = (const float*)d_in[9];
    const float* bih    = (const float*)d_in[10];
    const float* bhh    = (const float*)d_in[11];
    const float* convw  = (const float*)d_in[12];
    const float* convb  = (const float*)d_in[13];
    const float* dsb    = (const float*)d_in[14];

    float* outp = (float*)d_out;
    float* prob = outp + (size_t)NB*LSEQ*DDIM;
    float* sel  = prob + NB*KC*KC;

    char* p = (char*)d_ws;
    auto alloc = [&](size_t bytes)->char*{ char* r = p; p += (bytes + 255) & ~(size_t)255; return r; };
    __hip_bfloat16* gx    = (__hip_bfloat16*)alloc((size_t)16384*2048*2);
    __hip_bfloat16* hbf   = (__hip_bfloat16*)alloc((size_t)NB*LSEQ*DDIM*2);
    __hip_bfloat16* wihbf = (__hip_bfloat16*)alloc((size_t)2*2048*512*2);
    float*          bias2 = (float*)        alloc((size_t)2*2048*4);
    __hip_bfloat16* out1  = (__hip_bfloat16*)alloc((size_t)NB*LSEQ*DDIM*2);
    __hip_bfloat16* out2  = (__hip_bfloat16*)alloc((size_t)NB*LSEQ*DDIM*2);
    __hip_bfloat16* wtc   = (__hip_bfloat16*)alloc((size_t)11*512*512*2);
    float*          pf    = (float*)        alloc((size_t)NB*KC*KC*128*4);
    int*            pos   = (int*)          alloc((size_t)NB*KC*4);
    float*          cm    = (float*)        alloc((size_t)NB*LSEQ*4);
    float*          win   = (float*)        alloc((size_t)NB*LSEQ*4);
    int*            cnt1  = (int*)          alloc((size_t)512*4);
    int*            cnt2  = cnt1 + 128;

    // 1) prep: casts (wihbf/bias2 gate-interleaved), conv-w transpose, pos/cm/win, counters
    k_prep<<<6169, 256, 0, stream>>>(hidden, hbf, Wih, wihbf, bih, bhh, bias2, convw, wtc, aa, pos, cm, win, cnt1);
    // 2) recur L1 || gemm L1 (producer, counter-signaled) || bilinear
    k_fused1<<<16 + 2048 + 1024, 512, 0, stream>>>(Whh, gx, out1, cnt1, hbf, wihbf, bias2,
                                                   hidden, pos, Wbil, bbil, pf);
    // 3) recur L2 || gemm L2 || cls+greedy
    k_fused2<<<16 + 2048 + 8, 512, 0, stream>>>(Whh, gx, out2, cnt2, out1, wihbf, bias2,
                                                pf, w1, b1, w2, b2, pos, prob, sel);
    // 4) conv (+ce) + final fusion, co-split for wt L2 residency
    k_convce<<<512, 256, 0, stream>>>(hidden, out2, win, cm, dsb, wtc, convb, outp);
}

// Round 12
// 5199.716 us; speedup vs baseline: 4.7750x; 4.7750x over previous
//
#include <hip/hip_runtime.h>
#include <hip/hip_bf16.h>

typedef float  f32x4 __attribute__((ext_vector_type(4)));
typedef float  f32x2 __attribute__((ext_vector_type(2)));
typedef int    i32x4 __attribute__((ext_vector_type(4)));
typedef int    i32x8 __attribute__((ext_vector_type(8)));

#define NB   8
#define LSEQ 2048
#define DDIM 512
#define KC   16

__device__ __forceinline__ float rcp_(float x){ return __builtin_amdgcn_rcpf(x); }
__device__ __forceinline__ float ex2_(float x){ return __builtin_amdgcn_exp2f(x); }
__device__ __forceinline__ float clamp60(float x){ return fminf(fmaxf(x, -60.f), 60.f); }
__device__ __forceinline__ float blo(unsigned u){ return __uint_as_float(u<<16); }
__device__ __forceinline__ float bhi(unsigned u){ return __uint_as_float(u & 0xffff0000u); }
__device__ __forceinline__ unsigned pk2(float a, float b){
    __hip_bfloat16 x=__float2bfloat16(a), y=__float2bfloat16(b);
    return (unsigned)*(unsigned short*)&x | ((unsigned)*(unsigned short*)&y<<16);
}

#define GLDS(gp, lp) __builtin_amdgcn_global_load_lds(                      \
    (__attribute__((address_space(1))) const void*)(gp),                   \
    (__attribute__((address_space(3))) void*)(lp), 16, 0, 0)

// ================= prep: casts + bias + convw + poswin + counter zero =================
// wihbf/bias2 gate-interleaved: out row (lp, p*4+q) = src row (lp, q*256+p).
__global__ __launch_bounds__(256) void k_prep(const float* __restrict__ hidden, __hip_bfloat16* __restrict__ hbf,
                                              const float* __restrict__ Wih, __hip_bfloat16* __restrict__ wihbf,
                                              const float* __restrict__ bih, const float* __restrict__ bhh,
                                              float* __restrict__ bias2,
                                              const float* __restrict__ convw, __hip_bfloat16* __restrict__ wtc,
                                              const int* __restrict__ aa, int* __restrict__ pos,
                                              float* __restrict__ cm, float* __restrict__ win,
                                              int* __restrict__ cnt){
    int bid = blockIdx.x, tid = threadIdx.x;
    if(bid < 4096){                                  // cast hidden -> bf16 (x8)
        size_t i = (size_t)bid*256 + tid;
        const f32x4* s = (const f32x4*)(hidden + i*8);
        f32x4 v0 = s[0], v1 = s[1];
        i32x4 o; o.x = pk2(v0.x,v0.y); o.y = pk2(v0.z,v0.w);
                 o.z = pk2(v1.x,v1.y); o.w = pk2(v1.z,v1.w);
        ((i32x4*)hbf)[i] = o;
    } else if(bid < 5120){                           // cast Wih -> bf16, gate-interleaved rows
        size_t o = ((size_t)(bid-4096)*256 + tid) * 8;
        int Rp  = (int)(o >> 9);
        int col = (int)(o & 511);
        int lp  = Rp >> 10;
        int base= Rp & 1023;
        int p = base >> 2, q = base & 3;
        int Rs = (lp<<10) + (q<<8) + p;
        const f32x4* s = (const f32x4*)(Wih + ((size_t)Rs << 9) + col);
        f32x4 v0 = s[0], v1 = s[1];
        i32x4 oo; oo.x = pk2(v0.x,v0.y); oo.y = pk2(v0.z,v0.w);
                  oo.z = pk2(v1.x,v1.y); oo.w = pk2(v1.z,v1.w);
        ((i32x4*)wihbf)[o>>3] = oo;
    } else if(bid < 5136){                           // bias2 = bih + bhh, gate-interleaved
        int i = (bid-5120)*256 + tid;
        int l = i >> 11, b2 = i & 2047;
        int dir = b2 >> 10, b = b2 & 1023;
        int p = b >> 2, q = b & 3;
        int src = ((l*2+dir)<<10) + (q<<8) + p;
        bias2[i] = bih[src] + bhh[src];
    } else if(bid < 6160){                           // conv_w transpose -> wt[tap][co][ci]
        int idx = (bid-5136)*256 + tid;
        #pragma unroll
        for(int tap=0; tap<11; ++tap)
            wtc[(size_t)tap*262144 + idx] = __float2bfloat16(convw[(size_t)idx*11 + tap]);
    } else if(bid < 6168){                           // poswin
        int b = bid - 6160;
        __shared__ unsigned char fl[LSEQ];
        for(int t=tid; t<LSEQ; t+=256) fl[t] = (aa[b*LSEQ+t]==4) ? 1 : 0;
        __syncthreads();
        if(tid==0){
            int c=0;
            for(int t=0; t<LSEQ && c<KC; ++t) if(fl[t]) pos[b*KC + c++] = t;
            for(; c<KC; ++c) pos[b*KC+c]=0;
        }
        for(int t=tid; t<LSEQ; t+=256){
            cm[b*LSEQ+t] = fl[t] ? 1.f : 0.f;
            int lo = t-5 < 0 ? 0 : t-5;
            int hi = t+5 > LSEQ-1 ? LSEQ-1 : t+5;
            float wv = 0.f;
            for(int u=lo; u<=hi; ++u) if(fl[u]) wv = 1.f;
            win[b*LSEQ+t] = wv;
        }
    } else {                                          // zero ready-counters (both layers)
        if(tid < 256) cnt[tid] = 0;
    }
}

// ================= GEMM guest: 128x128 tile, ready-counter release =================
// C-stores are VOLATILE (write-through to the coherence point) so the consumer's
// cache-bypassing reads can never observe stale per-XCD L2 lines.
__device__ __forceinline__ void gemm_body(char* smem, const __hip_bfloat16* __restrict__ A,
        const __hip_bfloat16* __restrict__ Bw, const float* __restrict__ bias,
        __hip_bfloat16* C, int* __restrict__ cnt, int g){
    const int KD = 512, N = 2048;
    int nt = g & 15;
    int j  = g >> 4;                       // [0,128)
    int kpos = j >> 3, bat = j & 7;
    int mt = bat*16 + ((kpos&1) ? (15 - (kpos>>1)) : (kpos>>1));
    __hip_bfloat16 (*As)[32] = (__hip_bfloat16(*)[32])smem;
    __hip_bfloat16 (*Bs)[32] = (__hip_bfloat16(*)[32])(smem + 8192);
    int tid = threadIdx.x, w = tid>>6, lane = tid&63, lo = lane&15, hi = lane>>4;
    int wm = w>>1, wn = w&1;
    f32x4 acc[2][4];
    #pragma unroll
    for(int s=0;s<2;s++){
        #pragma unroll
        for(int t2=0;t2<4;t2++) acc[s][t2] = (f32x4){0.f,0.f,0.f,0.f};
    }
    int lr = tid>>2, lc = (tid&3)*8;
    const __hip_bfloat16* Ab = A  + (size_t)(mt*128)*KD;
    const __hip_bfloat16* Bb = Bw + (size_t)(nt*128)*KD;
    for(int kk=0; kk<KD; kk+=32){
        __builtin_amdgcn_s_barrier();
        GLDS(Ab + (size_t)lr*KD + kk + lc, &As[lr][lc]);
        GLDS(Bb + (size_t)lr*KD + kk + lc, &Bs[lr][lc]);
        asm volatile("s_waitcnt vmcnt(0)" ::: "memory");
        __builtin_amdgcn_s_barrier();
        i32x4 av[2], bv[4];
        #pragma unroll
        for(int s=0;s<2;s++) av[s] = *(const i32x4*)(&As[wm*32+s*16+lo][hi*8]);
        #pragma unroll
        for(int t2=0;t2<4;t2++) bv[t2] = *(const i32x4*)(&Bs[wn*64+t2*16+lo][hi*8]);
        asm volatile("s_nop 1" ::);
        #pragma unroll
        for(int s=0;s<2;s++){
            #pragma unroll
            for(int t2=0;t2<4;t2++)
                asm volatile("v_mfma_f32_16x16x32_bf16 %0, %1, %2, %0" : "+v"(acc[s][t2]) : "v"(av[s]), "v"(bv[t2]));
        }
    }
    asm volatile("s_nop 7\n\ts_nop 7" ::);
    volatile unsigned short* Cv = (volatile unsigned short*)C;
    #pragma unroll
    for(int t2=0;t2<4;t2++){
        int n = nt*128 + wn*64 + t2*16 + lo;
        float bn = bias[n];
        #pragma unroll
        for(int s=0;s<2;s++){
            #pragma unroll
            for(int rr=0;rr<4;rr++){
                int m = mt*128 + wm*32 + s*16 + hi*4 + rr;
                __hip_bfloat16 hv = __float2bfloat16(acc[s][t2][rr] + bn);
                Cv[(size_t)m*N + n] = *(unsigned short*)&hv;
            }
        }
    }
    asm volatile("s_waitcnt vmcnt(0)" ::: "memory");
    __syncthreads();
    if(tid==0)
        __hip_atomic_fetch_add(cnt + mt, 1, __ATOMIC_RELEASE, __HIP_MEMORY_SCOPE_AGENT);
}

// ================= LSTM recurrence body =================
// One 512-thr WG per (batch,dir). Whh fp8 in AGPRs; 16 16x16x128 MFMAs; Gx read
// directly into registers via VOLATILE (cache-bypassing) loads — immune to stale
// per-XCD L2 lines from the layer-1 use of the same gx buffer. 2-step prefetch
// (~4000 cyc slack) hides the coherent-point latency. 1 barrier/step.
__device__ __forceinline__ void recur_body(char* smem, const float* __restrict__ Whh,
        const __hip_bfloat16* __restrict__ Gx, __hip_bfloat16* __restrict__ Hout,
        const int* __restrict__ cnt, int layer, int bat, int dir){
    unsigned char (*hb)[256] = (unsigned char(*)[256])smem;   // 2 x 256 (h fp8)
    const int tid = threadIdx.x, w = tid>>6, lane = tid&63, lo = lane&15, hi = lane>>4;
    for(int i=tid; i<128; i+=512) ((int*)smem)[i] = 0;

    // Whh fp8 fragments -> AGPR. i = q*2+s covers gate j = q*256 + w*32 + s*16 + lo
    i32x8 bf[8][2];
    const float* wbase = Whh + ((size_t)(layer*2 + dir)*1024)*256;
    #pragma unroll
    for(int q=0;q<4;q++){
        #pragma unroll
        for(int s=0;s<2;s++){
            int j = q*256 + w*32 + s*16 + lo;
            const float* wr = wbase + (size_t)j*256;
            #pragma unroll
            for(int c=0;c<2;c++){
                i32x8 v;
                #pragma unroll
                for(int u=0; u<8; ++u){
                    f32x4 wv = *(const f32x4*)(wr + c*128 + hi*32 + u*4);
                    int pk = __builtin_amdgcn_cvt_pk_fp8_f32(wv.x, wv.y, 0, false);
                    pk = __builtin_amdgcn_cvt_pk_fp8_f32(wv.z, wv.w, pk, true);
                    v[u] = pk;
                }
                bf[q*2+s][c] = v;
            }
        }
    }
    const int pm = w*32 + ((hi&1)<<4) + lo;
    float cst = 0.f;
    const __hip_bfloat16* gxb = Gx + (size_t)bat*LSEQ*2048 + dir*1024;
    const int cbase = bat*16;
    int mtr = -1;

    uint2 gc, gn;   // gx(t), gx(t+1) in registers
    {   // prologue: acquire first tile, load gx(0), gx(1) (volatile, cache-bypass)
        int tok0 = dir ? (LSEQ-1) : 0;
        int tok1 = dir ? (LSEQ-2) : 1;
        int mtn = cbase + (tok0>>7);
        if(lane==0){
            while(__hip_atomic_load(cnt+mtn, __ATOMIC_ACQUIRE, __HIP_MEMORY_SCOPE_AGENT) < 16)
                __builtin_amdgcn_s_sleep(2);
        }
        mtr = mtn;
        const volatile unsigned* g0 = (const volatile unsigned*)(gxb + (size_t)tok0*2048 + pm*4);
        const volatile unsigned* g1 = (const volatile unsigned*)(gxb + (size_t)tok1*2048 + pm*4);
        gc.x = g0[0]; gc.y = g0[1];
        gn.x = g1[0]; gn.y = g1[1];
    }
    asm volatile("s_waitcnt lgkmcnt(0)" ::: "memory");
    __builtin_amdgcn_s_barrier();
    __builtin_amdgcn_sched_barrier(0);

    for(int t=0; t<LSEQ; ++t){
        const int tt = dir ? (LSEQ-1-t) : t;
        const int hcur = t&1, hnxt = hcur^1;
        // prefetch gx(t+2) into register (poll ready-counter at tile crossings)
        uint2 gf2;
        {
            int tp = (t+2 < LSEQ) ? (t+2) : (LSEQ-1);
            int tok = dir ? (LSEQ-1-tp) : tp;
            int mtn = cbase + (tok>>7);
            if(mtn != mtr){
                if(lane==0){
                    while(__hip_atomic_load(cnt+mtn, __ATOMIC_ACQUIRE, __HIP_MEMORY_SCOPE_AGENT) < 16)
                        __builtin_amdgcn_s_sleep(2);
                }
                mtr = mtn;
            }
            const volatile unsigned* gp = (const volatile unsigned*)(gxb + (size_t)tok*2048 + pm*4);
            gf2.x = gp[0]; gf2.y = gp[1];
        }
        // A: broadcast h (fp8) slice for this lane's k-group (conflict-free)
        i32x8 af[2];
        #pragma unroll
        for(int c=0;c<2;c++){
            i32x4 v0 = *(const i32x4*)(&hb[hcur][c*128 + hi*32]);
            i32x4 v1 = *(const i32x4*)(&hb[hcur][c*128 + hi*32 + 16]);
            af[c] = __builtin_shufflevector(v0, v1, 0,1,2,3,4,5,6,7);
        }
        // 16 independent MFMAs
        f32x4 aa[8], ab[8];
        #pragma unroll
        for(int i=0;i<8;i++){ aa[i] = (f32x4){0.f,0.f,0.f,0.f}; ab[i] = (f32x4){0.f,0.f,0.f,0.f}; }
        asm volatile("s_nop 1" ::);
        #pragma unroll
        for(int i=0;i<8;i++)
            asm volatile("v_mfma_f32_16x16x128_f8f6f4 %0, %1, %2, %0"
                         : "+v"(aa[i]) : "v"(af[0]), "a"(bf[i][0]));
        #pragma unroll
        for(int i=0;i<8;i++)
            asm volatile("v_mfma_f32_16x16x128_f8f6f4 %0, %1, %2, %0"
                         : "+v"(ab[i]) : "v"(af[1]), "a"(bf[i][1]));
        asm volatile("s_nop 7\n\ts_nop 7" ::);
        {   // epilogue (gates in registers; gx from register ring)
            float aI = (hi&1) ? (aa[1][0]+ab[1][0]) : (aa[0][0]+ab[0][0]);
            float aF = (hi&1) ? (aa[3][0]+ab[3][0]) : (aa[2][0]+ab[2][0]);
            float aG = (hi&1) ? (aa[5][0]+ab[5][0]) : (aa[4][0]+ab[4][0]);
            float aO = (hi&1) ? (aa[7][0]+ab[7][0]) : (aa[6][0]+ab[6][0]);
            float gi = aI + blo(gc.x);
            float gf = aF + bhi(gc.x);
            float gg = aG + blo(gc.y);
            float go = aO + bhi(gc.y);
            float sf = rcp_(1.f + ex2_(gf * -1.44269504f));
            float ag = ex2_(clamp60(gg * 2.88539008f));
            float bi = ex2_(clamp60(gi * -1.44269504f));
            float it = (ag - 1.f) * rcp_((1.f + bi) * (ag + 1.f));
            float c  = sf*cst + it;
            cst = c;
            float ac = ex2_(clamp60(c * 2.88539008f));
            float bo = ex2_(clamp60(go * -1.44269504f));
            float h  = (ac - 1.f) * rcp_((1.f + bo) * (ac + 1.f));
            if(hi < 2){
                int pk = __builtin_amdgcn_cvt_pk_fp8_f32(h, h, 0, false);
                hb[hnxt][pm] = (unsigned char)(pk & 0xff);
                Hout[((size_t)bat*LSEQ + tt)*512 + dir*256 + pm] = __float2bfloat16(h);
            }
        }
        // publish hb only (gx register-tracked, stores free-run)
        asm volatile("s_waitcnt lgkmcnt(0)" ::: "memory");
        __builtin_amdgcn_s_barrier();
        __builtin_amdgcn_sched_barrier(0);
        gc = gn; gn = gf2;
    }
}

// ================= bilinear body =================
__device__ __forceinline__ void bilinear_body(char* smem, const float* __restrict__ hidden,
        const int* __restrict__ pos, const float* __restrict__ Wb, const float* __restrict__ bb,
        float* __restrict__ pf, int idx){
    int c = idx & 127, b = idx >> 7;
    float (*fl)[516] = (float(*)[516])smem;
    float (*tl)[516] = (float(*)[516])(smem + 33024);
    int tid = threadIdx.x;
    for(int i=tid; i<2048; i+=512){
        int k = i>>7, d = (i&127)*4;
        int p = pos[b*KC + k];
        f32x4 v = *(const f32x4*)(hidden + ((size_t)b*LSEQ + p)*DDIM + d);
        fl[k][d]=v.x; fl[k][d+1]=v.y; fl[k][d+2]=v.z; fl[k][d+3]=v.w;
    }
    __syncthreads();
    int e = tid;
    float acc[16];
    #pragma unroll
    for(int k=0;k<16;k++) acc[k]=0.f;
    const float* wc = Wb + (size_t)c*512*512;
    for(int d=0; d<512; ++d){
        float wv = wc[(size_t)d*512 + e];
        #pragma unroll
        for(int k=0;k<16;k++) acc[k] += fl[k][d]*wv;
    }
    #pragma unroll
    for(int k=0;k<16;k++) tl[k][e] = acc[k];
    __syncthreads();
    if(tid < 256){
        int kq = tid>>4, mq = tid&15;
        const f32x4* tp = (const f32x4*)&tl[kq][0];
        const f32x4* fp = (const f32x4*)&fl[mq][0];
        float s = 0.f;
        #pragma unroll 8
        for(int e2=0;e2<128;e2++){ f32x4 a=tp[e2], v=fp[e2]; s += a.x*v.x + a.y*v.y + a.z*v.z + a.w*v.w; }
        pf[(((size_t)b*16+kq)*16+mq)*128 + c] = s + bb[c];
    }
}

// ================= cls + greedy body =================
__device__ __forceinline__ void clsgreedy_body(char* smem, const float* __restrict__ pf,
        const float* __restrict__ w1, const float* __restrict__ b1,
        const float* __restrict__ w2, const float* __restrict__ b2,
        const int* __restrict__ pos, float* __restrict__ prob, float* __restrict__ sel, int b){
    float (*sw1)[128] = (float(*)[128])smem;
    float* sw2 = (float*)(smem + 32768);
    float* sb1 = sw2 + 64;
    float* sp  = sb1 + 64;
    unsigned char* si = (unsigned char*)(sp + 120);
    unsigned char* sj = si + 120;
    int tid = threadIdx.x;
    for(int i=tid; i<8192; i+=512) sw1[i>>7][i&127] = w1[i];
    if(tid<64){ sw2[tid]=w2[tid]; sb1[tid]=b1[tid]; }
    if(tid==0){
        int idx=0;
        for(int i=0;i<16;i++) for(int j=i+1;j<16;j++){ si[idx]=(unsigned char)i; sj[idx]=(unsigned char)j; idx++; }
    }
    if(tid<256) sel[b*256+tid] = 0.f;
    __syncthreads();
    if(tid < 256){
        int k = tid>>4, m = tid&15;
        const f32x4* pp = (const f32x4*)(pf + (((size_t)b*16+k)*16+m)*128);
        f32x4 pr[32];
        #pragma unroll
        for(int i=0;i<32;i++) pr[i] = pp[i];
        float lg = b2[0];
        for(int n=0;n<64;n++){
            const f32x4* wr = (const f32x4*)&sw1[n][0];
            float a = sb1[n];
            #pragma unroll
            for(int i=0;i<32;i++){ f32x4 wv = wr[i]; a += pr[i].x*wv.x + pr[i].y*wv.y + pr[i].z*wv.z + pr[i].w*wv.w; }
            a = fmaxf(a, 0.f);
            lg += a*sw2[n];
        }
        float p = rcp_(1.f + ex2_(lg * -1.44269504f));
        int dk = pos[b*16+k]-pos[b*16+m]; if(dk<0) dk=-dk;
        if(dk<2) p *= 0.1f;
        prob[b*256 + k*16 + m] = p;
        if(k < m) sp[k*(31-k)/2 + (m-k-1)] = p;
    }
    __syncthreads();
    if(tid==0){
        bool done[120]; bool used[16];
        for(int i=0;i<120;i++) done[i]=false;
        for(int i=0;i<16;i++)  used[i]=false;
        for(int it=0; it<120; ++it){
            int bi=-1; float bp=-1e30f;
            for(int q=0;q<120;q++) if(!done[q] && sp[q]>bp){ bp=sp[q]; bi=q; }
            done[bi]=true;
            if(bp>0.5f && !used[si[bi]] && !used[sj[bi]]){
                used[si[bi]]=true; used[sj[bi]]=true;
                sel[b*256 + si[bi]*16 + sj[bi]] = 1.f;
            }
        }
    }
}

// ================= fused launches =================
__global__ __launch_bounds__(512) void k_fused1(const float* __restrict__ Whh, __hip_bfloat16* __restrict__ Gx,
        __hip_bfloat16* __restrict__ Hout, int* __restrict__ cnt,
        const __hip_bfloat16* __restrict__ hbf, const __hip_bfloat16* __restrict__ wihbf,
        const float* __restrict__ bias2,
        const float* __restrict__ hidden, const int* __restrict__ pos,
        const float* __restrict__ Wbil, const float* __restrict__ bbil, float* __restrict__ pf){
    __shared__ __attribute__((aligned(16))) char smem[98304];
    int bid = blockIdx.x;
    if(bid < 16){
        recur_body(smem, Whh, Gx, Hout, cnt, 0, bid>>1, bid&1);
    } else if(bid < 16 + 2048){
        gemm_body(smem, hbf, wihbf, bias2, Gx, cnt, bid - 16);
    } else {
        bilinear_body(smem, hidden, pos, Wbil, bbil, pf, bid - 2064);
    }
}

__global__ __launch_bounds__(512) void k_fused2(const float* __restrict__ Whh, __hip_bfloat16* __restrict__ Gx,
        __hip_bfloat16* __restrict__ Hout, int* __restrict__ cnt,
        const __hip_bfloat16* __restrict__ out1, const __hip_bfloat16* __restrict__ wihbf,
        const float* __restrict__ bias2,
        const float* __restrict__ pf, const float* __restrict__ w1, const float* __restrict__ b1,
        const float* __restrict__ w2, const float* __restrict__ b2, const int* __restrict__ pos,
        float* __restrict__ prob, float* __restrict__ sel){
    __shared__ __attribute__((aligned(16))) char smem[98304];
    int bid = blockIdx.x;
    if(bid < 16){
        recur_body(smem, Whh, Gx, Hout, cnt, 1, bid>>1, bid&1);
    } else if(bid < 16 + 2048){
        gemm_body(smem, out1, wihbf + (size_t)2048*512, bias2 + 2048, Gx, cnt, bid - 16);
    } else {
        clsgreedy_body(smem, pf, w1, b1, w2, b2, pos, prob, sel, bid - 2064);
    }
}

// ================= conv (ce computed in staging) + final fusion =================
// co split in halves; XCD-parity mapping keeps one 2.88MB wt-half L2-resident per XCD.
__global__ __launch_bounds__(256) void k_convce(const float* __restrict__ hs, const __hip_bfloat16* __restrict__ opt,
        const float* __restrict__ win, const float* __restrict__ cm, const float* __restrict__ dsb,
        const __hip_bfloat16* __restrict__ wt, const float* __restrict__ convb, float* __restrict__ outp){
    int xcd = blockIdx.x & 7;          // MI355X round-robin dispatch heuristic (perf-only)
    int j   = blockIdx.x >> 3;         // [0,64)
    int coH = xcd & 1;
    int tix = (xcd >> 1) * 64 + j;     // [0,256)
    int mt  = tix >> 3, b = tix & 7;
    __shared__ __hip_bfloat16 S[74][520];
    int tid = threadIdx.x;
    for(int i=tid; i<74*64; i+=256){
        int rq = i>>6, cc = (i&63)*8;
        int tok = mt*64 - 5 + rq;
        i32x4 o = (i32x4){0,0,0,0};
        if(tok>=0 && tok<LSEQ){
            size_t base = ((size_t)b*LSEQ + tok)*512 + cc;
            float wv = win[b*LSEQ+tok]*0.4f, cv = cm[b*LSEQ+tok];
            f32x4 h0 = *(const f32x4*)(hs + base);
            f32x4 h1 = *(const f32x4*)(hs + base + 4);
            unsigned long long u0 = *(const unsigned long long*)(opt + base);
            unsigned long long u1 = *(const unsigned long long*)(opt + base + 4);
            f32x4 d0 = *(const f32x4*)(dsb + cc);
            f32x4 d1 = *(const f32x4*)(dsb + cc + 4);
            float c0 = h0.x + wv*__uint_as_float((unsigned)(u0      & 0xffffull)<<16) + d0.x*cv;
            float c1 = h0.y + wv*__uint_as_float((unsigned)((u0>>16)& 0xffffull)<<16) + d0.y*cv;
            float c2 = h0.z + wv*__uint_as_float((unsigned)((u0>>32)& 0xffffull)<<16) + d0.z*cv;
            float c3 = h0.w + wv*__uint_as_float((unsigned)((u0>>48)& 0xffffull)<<16) + d0.w*cv;
            float c4 = h1.x + wv*__uint_as_float((unsigned)(u1      & 0xffffull)<<16) + d1.x*cv;
            float c5 = h1.y + wv*__uint_as_float((unsigned)((u1>>16)& 0xffffull)<<16) + d1.y*cv;
            float c6 = h1.z + wv*__uint_as_float((unsigned)((u1>>32)& 0xffffull)<<16) + d1.z*cv;
            float c7 = h1.w + wv*__uint_as_float((unsigned)((u1>>48)& 0xffffull)<<16) + d1.w*cv;
            o.x = pk2(c0,c1); o.y = pk2(c2,c3); o.z = pk2(c4,c5); o.w = pk2(c6,c7);
        }
        *(i32x4*)(&S[rq][cc]) = o;
    }
    __syncthreads();
    int w = tid>>6, lane = tid&63, lo = lane&15, hi = lane>>4;
    f32x4 acc[4][4];                    // [ms][s] — co slice = coH*256 + w*64 + s*16 + lo
    #pragma unroll
    for(int ms=0;ms<4;ms++){
        #pragma unroll
        for(int s=0;s<4;s++) acc[ms][s] = (f32x4){0.f,0.f,0.f,0.f};
    }
    asm volatile("s_nop 1" ::);
    for(int tap=0; tap<11; ++tap){
        const __hip_bfloat16* wtp = wt + (size_t)tap*262144 + (size_t)(coH*256 + w*64)*512;
        for(int kk=0; kk<512; kk+=32){
            i32x4 a[4];
            #pragma unroll
            for(int ms=0;ms<4;ms++) a[ms] = *(const i32x4*)(&S[ms*16 + lo + tap][kk + hi*8]);
            #pragma unroll
            for(int s=0;s<4;s++){
                i32x4 bq = *(const i32x4*)(wtp + (size_t)(s*16 + lo)*512 + kk + hi*8);
                #pragma unroll
                for(int ms=0;ms<4;ms++)
                    asm volatile("v_mfma_f32_16x16x32_bf16 %0, %1, %2, %0" : "+v"(acc[ms][s]) : "v"(a[ms]), "v"(bq));
            }
        }
    }
    asm volatile("s_nop 7\n\ts_nop 7" ::);
    #pragma unroll
    for(int s=0;s<4;s++){
        int co = coH*256 + w*64 + s*16 + lo;
        float cb = convb[co];
        #pragma unroll
        for(int ms=0;ms<4;ms++){
            #pragma unroll
            for(int rr=0; rr<4; ++rr){
                int row = ms*16 + hi*4 + rr;
                int tok = mt*64 + row;
                size_t gi = ((size_t)b*LSEQ + tok)*512 + co;
                float h   = hs[gi];
                float cef = __bfloat162float(S[row + 5][co]);
                outp[gi] = 0.5f*h + 0.3f*cef + 0.2f*(acc[ms][s][rr] + cb);
            }
        }
    }
}

// ================= launch =================
extern "C" void kernel_launch(void* const* d_in, const int* in_sizes, int n_in,
                              void* d_out, int out_size, void* d_ws, size_t ws_size,
                              hipStream_t stream)
{
    (void)in_sizes; (void)n_in; (void)out_size; (void)ws_size;
    const float* hidden = (const float*)d_in[0];
    const int*   aa     = (const int*)d_in[1];
    const float* Wbil   = (const float*)d_in[2];
    const float* bbil   = (const float*)d_in[3];
    const float* w1     = (const float*)d_in[4];
    const float* b1     = (const float*)d_in[5];
    const float* w2     = (const float*)d_in[6];
    const float* b2     = (const float*)d_in[7];
    const float* Wih    = (const float*)d_in[8];
    const float* Whh    = (const float*)d_in[9];
    const float* bih    = (const float*)d_in[10];
    const float* bhh    = (const float*)d_in[11];
    const float* convw  = (const float*)d_in[12];
    const float* convb  = (const float*)d_in[13];
    const float* dsb    = (const float*)d_in[14];

    float* outp = (float*)d_out;
    float* prob = outp + (size_t)NB*LSEQ*DDIM;
    float* sel  = prob + NB*KC*KC;

    char* p = (char*)d_ws;
    auto alloc = [&](size_t bytes)->char*{ char* r = p; p += (bytes + 255) & ~(size_t)255; return r; };
    __hip_bfloat16* gx    = (__hip_bfloat16*)alloc((size_t)16384*2048*2);
    __hip_bfloat16* hbf   = (__hip_bfloat16*)alloc((size_t)NB*LSEQ*DDIM*2);
    __hip_bfloat16* wihbf = (__hip_bfloat16*)alloc((size_t)2*2048*512*2);
    float*          bias2 = (float*)        alloc((size_t)2*2048*4);
    __hip_bfloat16* out1  = (__hip_bfloat16*)alloc((size_t)NB*LSEQ*DDIM*2);
    __hip_bfloat16* out2  = (__hip_bfloat16*)alloc((size_t)NB*LSEQ*DDIM*2);
    __hip_bfloat16* wtc   = (__hip_bfloat16*)alloc((size_t)11*512*512*2);
    float*          pf    = (float*)        alloc((size_t)NB*KC*KC*128*4);
    int*            pos   = (int*)          alloc((size_t)NB*KC*4);
    float*          cm    = (float*)        alloc((size_t)NB*LSEQ*4);
    float*          win   = (float*)        alloc((size_t)NB*LSEQ*4);
    int*            cnt1  = (int*)          alloc((size_t)512*4);
    int*            cnt2  = cnt1 + 128;

    // 1) prep: casts (wihbf/bias2 gate-interleaved), conv-w transpose, pos/cm/win, counters
    k_prep<<<6169, 256, 0, stream>>>(hidden, hbf, Wih, wihbf, bih, bhh, bias2, convw, wtc, aa, pos, cm, win, cnt1);
    // 2) recur L1 || gemm L1 (producer, counter-signaled) || bilinear
    k_fused1<<<16 + 2048 + 1024, 512, 0, stream>>>(Whh, gx, out1, cnt1, hbf, wihbf, bias2,
                                                   hidden, pos, Wbil, bbil, pf);
    // 3) recur L2 || gemm L2 || cls+greedy
    k_fused2<<<16 + 2048 + 8, 512, 0, stream>>>(Whh, gx, out2, cnt2, out1, wihbf, bias2,
                                                pf, w1, b1, w2, b2, pos, prob, sel);
    // 4) conv (+ce) + final fusion, co-split for wt L2 residency
    k_convce<<<512, 256, 0, stream>>>(hidden, out2, win, cm, dsb, wtc, convb, outp);
}

// Round 13
// 3827.867 us; speedup vs baseline: 6.4863x; 1.3584x over previous
//
#include <hip/hip_runtime.h>
#include <hip/hip_bf16.h>

typedef float  f32x4 __attribute__((ext_vector_type(4)));
typedef float  f32x2 __attribute__((ext_vector_type(2)));
typedef int    i32x4 __attribute__((ext_vector_type(4)));
typedef int    i32x8 __attribute__((ext_vector_type(8)));

#define NB   8
#define LSEQ 2048
#define DDIM 512
#define KC   16

__device__ __forceinline__ float rcp_(float x){ return __builtin_amdgcn_rcpf(x); }
__device__ __forceinline__ float ex2_(float x){ return __builtin_amdgcn_exp2f(x); }
__device__ __forceinline__ float clamp60(float x){ return fminf(fmaxf(x, -60.f), 60.f); }
__device__ __forceinline__ float blo(unsigned u){ return __uint_as_float(u<<16); }
__device__ __forceinline__ float bhi(unsigned u){ return __uint_as_float(u & 0xffff0000u); }
__device__ __forceinline__ unsigned pk2(float a, float b){
    __hip_bfloat16 x=__float2bfloat16(a), y=__float2bfloat16(b);
    return (unsigned)*(unsigned short*)&x | ((unsigned)*(unsigned short*)&y<<16);
}

#define GLDS(gp, lp) __builtin_amdgcn_global_load_lds(                      \
    (__attribute__((address_space(1))) const void*)(gp),                   \
    (__attribute__((address_space(3))) void*)(lp), 16, 0, 0)

// ================= prep: casts + bias + convw + poswin + counter zero =================
// wihbf/bias2 gate-interleaved: out row (lp, p*4+q) = src row (lp, q*256+p).
__global__ __launch_bounds__(256) void k_prep(const float* __restrict__ hidden, __hip_bfloat16* __restrict__ hbf,
                                              const float* __restrict__ Wih, __hip_bfloat16* __restrict__ wihbf,
                                              const float* __restrict__ bih, const float* __restrict__ bhh,
                                              float* __restrict__ bias2,
                                              const float* __restrict__ convw, __hip_bfloat16* __restrict__ wtc,
                                              const int* __restrict__ aa, int* __restrict__ pos,
                                              float* __restrict__ cm, float* __restrict__ win,
                                              int* __restrict__ cnt){
    int bid = blockIdx.x, tid = threadIdx.x;
    if(bid < 4096){                                  // cast hidden -> bf16 (x8)
        size_t i = (size_t)bid*256 + tid;
        const f32x4* s = (const f32x4*)(hidden + i*8);
        f32x4 v0 = s[0], v1 = s[1];
        i32x4 o; o.x = pk2(v0.x,v0.y); o.y = pk2(v0.z,v0.w);
                 o.z = pk2(v1.x,v1.y); o.w = pk2(v1.z,v1.w);
        ((i32x4*)hbf)[i] = o;
    } else if(bid < 5120){                           // cast Wih -> bf16, gate-interleaved rows
        size_t o = ((size_t)(bid-4096)*256 + tid) * 8;
        int Rp  = (int)(o >> 9);
        int col = (int)(o & 511);
        int lp  = Rp >> 10;
        int base= Rp & 1023;
        int p = base >> 2, q = base & 3;
        int Rs = (lp<<10) + (q<<8) + p;
        const f32x4* s = (const f32x4*)(Wih + ((size_t)Rs << 9) + col);
        f32x4 v0 = s[0], v1 = s[1];
        i32x4 oo; oo.x = pk2(v0.x,v0.y); oo.y = pk2(v0.z,v0.w);
                  oo.z = pk2(v1.x,v1.y); oo.w = pk2(v1.z,v1.w);
        ((i32x4*)wihbf)[o>>3] = oo;
    } else if(bid < 5136){                           // bias2 = bih + bhh, gate-interleaved
        int i = (bid-5120)*256 + tid;
        int l = i >> 11, b2 = i & 2047;
        int dir = b2 >> 10, b = b2 & 1023;
        int p = b >> 2, q = b & 3;
        int src = ((l*2+dir)<<10) + (q<<8) + p;
        bias2[i] = bih[src] + bhh[src];
    } else if(bid < 6160){                           // conv_w transpose -> wt[tap][co][ci]
        int idx = (bid-5136)*256 + tid;
        #pragma unroll
        for(int tap=0; tap<11; ++tap)
            wtc[(size_t)tap*262144 + idx] = __float2bfloat16(convw[(size_t)idx*11 + tap]);
    } else if(bid < 6168){                           // poswin
        int b = bid - 6160;
        __shared__ unsigned char fl[LSEQ];
        for(int t=tid; t<LSEQ; t+=256) fl[t] = (aa[b*LSEQ+t]==4) ? 1 : 0;
        __syncthreads();
        if(tid==0){
            int c=0;
            for(int t=0; t<LSEQ && c<KC; ++t) if(fl[t]) pos[b*KC + c++] = t;
            for(; c<KC; ++c) pos[b*KC+c]=0;
        }
        for(int t=tid; t<LSEQ; t+=256){
            cm[b*LSEQ+t] = fl[t] ? 1.f : 0.f;
            int lo = t-5 < 0 ? 0 : t-5;
            int hi = t+5 > LSEQ-1 ? LSEQ-1 : t+5;
            float wv = 0.f;
            for(int u=lo; u<=hi; ++u) if(fl[u]) wv = 1.f;
            win[b*LSEQ+t] = wv;
        }
    } else {                                          // zero ready-counters (both layers)
        if(tid < 256) cnt[tid] = 0;
    }
}

// ================= GEMM guest: 128x128 tile, ready-counter release =================
// C-stores are VOLATILE (write-through toward the coherence point); consumer reads
// are agent-scope coherent loads, so no stale per-XCD L2 line can be observed.
__device__ __forceinline__ void gemm_body(char* smem, const __hip_bfloat16* __restrict__ A,
        const __hip_bfloat16* __restrict__ Bw, const float* __restrict__ bias,
        __hip_bfloat16* C, int* __restrict__ cnt, int g){
    const int KD = 512, N = 2048;
    int nt = g & 15;
    int j  = g >> 4;                       // [0,128)
    int kpos = j >> 3, bat = j & 7;
    int mt = bat*16 + ((kpos&1) ? (15 - (kpos>>1)) : (kpos>>1));
    __hip_bfloat16 (*As)[32] = (__hip_bfloat16(*)[32])smem;
    __hip_bfloat16 (*Bs)[32] = (__hip_bfloat16(*)[32])(smem + 8192);
    int tid = threadIdx.x, w = tid>>6, lane = tid&63, lo = lane&15, hi = lane>>4;
    int wm = w>>1, wn = w&1;
    f32x4 acc[2][4];
    #pragma unroll
    for(int s=0;s<2;s++){
        #pragma unroll
        for(int t2=0;t2<4;t2++) acc[s][t2] = (f32x4){0.f,0.f,0.f,0.f};
    }
    int lr = tid>>2, lc = (tid&3)*8;
    const __hip_bfloat16* Ab = A  + (size_t)(mt*128)*KD;
    const __hip_bfloat16* Bb = Bw + (size_t)(nt*128)*KD;
    for(int kk=0; kk<KD; kk+=32){
        __builtin_amdgcn_s_barrier();
        GLDS(Ab + (size_t)lr*KD + kk + lc, &As[lr][lc]);
        GLDS(Bb + (size_t)lr*KD + kk + lc, &Bs[lr][lc]);
        asm volatile("s_waitcnt vmcnt(0)" ::: "memory");
        __builtin_amdgcn_s_barrier();
        i32x4 av[2], bv[4];
        #pragma unroll
        for(int s=0;s<2;s++) av[s] = *(const i32x4*)(&As[wm*32+s*16+lo][hi*8]);
        #pragma unroll
        for(int t2=0;t2<4;t2++) bv[t2] = *(const i32x4*)(&Bs[wn*64+t2*16+lo][hi*8]);
        asm volatile("s_nop 1" ::);
        #pragma unroll
        for(int s=0;s<2;s++){
            #pragma unroll
            for(int t2=0;t2<4;t2++)
                asm volatile("v_mfma_f32_16x16x32_bf16 %0, %1, %2, %0" : "+v"(acc[s][t2]) : "v"(av[s]), "v"(bv[t2]));
        }
    }
    asm volatile("s_nop 7\n\ts_nop 7" ::);
    volatile unsigned short* Cv = (volatile unsigned short*)C;
    #pragma unroll
    for(int t2=0;t2<4;t2++){
        int n = nt*128 + wn*64 + t2*16 + lo;
        float bn = bias[n];
        #pragma unroll
        for(int s=0;s<2;s++){
            #pragma unroll
            for(int rr=0;rr<4;rr++){
                int m = mt*128 + wm*32 + s*16 + hi*4 + rr;
                __hip_bfloat16 hv = __float2bfloat16(acc[s][t2][rr] + bn);
                Cv[(size_t)m*N + n] = *(unsigned short*)&hv;
            }
        }
    }
    asm volatile("s_waitcnt vmcnt(0)" ::: "memory");
    __syncthreads();
    if(tid==0)
        __hip_atomic_fetch_add(cnt + mt, 1, __ATOMIC_RELEASE, __HIP_MEMORY_SCOPE_AGENT);
}

// ================= LSTM recurrence body =================
// One 512-thr WG per (batch,dir). Whh fp8 in AGPRs; 16 16x16x128 MFMAs; Gx read
// directly into registers via RELAXED AGENT-SCOPE atomic 8B loads — coherent
// (cache-bypassing, immune to stale per-XCD L2 lines) but pipelined: waitcnt is
// compiler-managed, latency hidden by the 2-step prefetch ring. 1 barrier/step.
__device__ __forceinline__ void recur_body(char* smem, const float* __restrict__ Whh,
        const __hip_bfloat16* __restrict__ Gx, __hip_bfloat16* __restrict__ Hout,
        const int* __restrict__ cnt, int layer, int bat, int dir){
    unsigned char (*hb)[256] = (unsigned char(*)[256])smem;   // 2 x 256 (h fp8)
    const int tid = threadIdx.x, w = tid>>6, lane = tid&63, lo = lane&15, hi = lane>>4;
    for(int i=tid; i<128; i+=512) ((int*)smem)[i] = 0;

    // Whh fp8 fragments -> AGPR. i = q*2+s covers gate j = q*256 + w*32 + s*16 + lo
    i32x8 bf[8][2];
    const float* wbase = Whh + ((size_t)(layer*2 + dir)*1024)*256;
    #pragma unroll
    for(int q=0;q<4;q++){
        #pragma unroll
        for(int s=0;s<2;s++){
            int j = q*256 + w*32 + s*16 + lo;
            const float* wr = wbase + (size_t)j*256;
            #pragma unroll
            for(int c=0;c<2;c++){
                i32x8 v;
                #pragma unroll
                for(int u=0; u<8; ++u){
                    f32x4 wv = *(const f32x4*)(wr + c*128 + hi*32 + u*4);
                    int pk = __builtin_amdgcn_cvt_pk_fp8_f32(wv.x, wv.y, 0, false);
                    pk = __builtin_amdgcn_cvt_pk_fp8_f32(wv.z, wv.w, pk, true);
                    v[u] = pk;
                }
                bf[q*2+s][c] = v;
            }
        }
    }
    const int pm = w*32 + ((hi&1)<<4) + lo;
    float cst = 0.f;
    const __hip_bfloat16* gxb = Gx + (size_t)bat*LSEQ*2048 + dir*1024;
    const int cbase = bat*16;
    int mtr = -1;

    unsigned long long gc, gn;   // gx(t), gx(t+1) in registers (4 gates x bf16)
    {   // prologue: acquire first tile, load gx(0), gx(1) (coherent 8B loads)
        int tok0 = dir ? (LSEQ-1) : 0;
        int tok1 = dir ? (LSEQ-2) : 1;
        int mtn = cbase + (tok0>>7);
        if(lane==0){
            while(__hip_atomic_load(cnt+mtn, __ATOMIC_ACQUIRE, __HIP_MEMORY_SCOPE_AGENT) < 16)
                __builtin_amdgcn_s_sleep(2);
        }
        mtr = mtn;
        gc = __hip_atomic_load((const unsigned long long*)(gxb + (size_t)tok0*2048 + pm*4),
                               __ATOMIC_RELAXED, __HIP_MEMORY_SCOPE_AGENT);
        gn = __hip_atomic_load((const unsigned long long*)(gxb + (size_t)tok1*2048 + pm*4),
                               __ATOMIC_RELAXED, __HIP_MEMORY_SCOPE_AGENT);
    }
    asm volatile("s_waitcnt lgkmcnt(0)" ::: "memory");
    __builtin_amdgcn_s_barrier();
    __builtin_amdgcn_sched_barrier(0);

    for(int t=0; t<LSEQ; ++t){
        const int tt = dir ? (LSEQ-1-t) : t;
        const int hcur = t&1, hnxt = hcur^1;
        // prefetch gx(t+2) into register (poll ready-counter at tile crossings)
        unsigned long long gf2;
        {
            int tp = (t+2 < LSEQ) ? (t+2) : (LSEQ-1);
            int tok = dir ? (LSEQ-1-tp) : tp;
            int mtn = cbase + (tok>>7);
            if(mtn != mtr){
                if(lane==0){
                    while(__hip_atomic_load(cnt+mtn, __ATOMIC_ACQUIRE, __HIP_MEMORY_SCOPE_AGENT) < 16)
                        __builtin_amdgcn_s_sleep(2);
                }
                mtr = mtn;
            }
            gf2 = __hip_atomic_load((const unsigned long long*)(gxb + (size_t)tok*2048 + pm*4),
                                    __ATOMIC_RELAXED, __HIP_MEMORY_SCOPE_AGENT);
        }
        // A: broadcast h (fp8) slice for this lane's k-group (conflict-free)
        i32x8 af[2];
        #pragma unroll
        for(int c=0;c<2;c++){
            i32x4 v0 = *(const i32x4*)(&hb[hcur][c*128 + hi*32]);
            i32x4 v1 = *(const i32x4*)(&hb[hcur][c*128 + hi*32 + 16]);
            af[c] = __builtin_shufflevector(v0, v1, 0,1,2,3,4,5,6,7);
        }
        // 16 independent MFMAs
        f32x4 aa[8], ab[8];
        #pragma unroll
        for(int i=0;i<8;i++){ aa[i] = (f32x4){0.f,0.f,0.f,0.f}; ab[i] = (f32x4){0.f,0.f,0.f,0.f}; }
        asm volatile("s_nop 1" ::);
        #pragma unroll
        for(int i=0;i<8;i++)
            asm volatile("v_mfma_f32_16x16x128_f8f6f4 %0, %1, %2, %0"
                         : "+v"(aa[i]) : "v"(af[0]), "a"(bf[i][0]));
        #pragma unroll
        for(int i=0;i<8;i++)
            asm volatile("v_mfma_f32_16x16x128_f8f6f4 %0, %1, %2, %0"
                         : "+v"(ab[i]) : "v"(af[1]), "a"(bf[i][1]));
        asm volatile("s_nop 7\n\ts_nop 7" ::);
        {   // epilogue (gates in registers; gx from register ring)
            float aI = (hi&1) ? (aa[1][0]+ab[1][0]) : (aa[0][0]+ab[0][0]);
            float aF = (hi&1) ? (aa[3][0]+ab[3][0]) : (aa[2][0]+ab[2][0]);
            float aG = (hi&1) ? (aa[5][0]+ab[5][0]) : (aa[4][0]+ab[4][0]);
            float aO = (hi&1) ? (aa[7][0]+ab[7][0]) : (aa[6][0]+ab[6][0]);
            unsigned gcx = (unsigned)gc, gcy = (unsigned)(gc>>32);
            float gi = aI + blo(gcx);
            float gf = aF + bhi(gcx);
            float gg = aG + blo(gcy);
            float go = aO + bhi(gcy);
            float sf = rcp_(1.f + ex2_(gf * -1.44269504f));
            float ag = ex2_(clamp60(gg * 2.88539008f));
            float bi = ex2_(clamp60(gi * -1.44269504f));
            float it = (ag - 1.f) * rcp_((1.f + bi) * (ag + 1.f));
            float c  = sf*cst + it;
            cst = c;
            float ac = ex2_(clamp60(c * 2.88539008f));
            float bo = ex2_(clamp60(go * -1.44269504f));
            float h  = (ac - 1.f) * rcp_((1.f + bo) * (ac + 1.f));
            if(hi < 2){
                int pk = __builtin_amdgcn_cvt_pk_fp8_f32(h, h, 0, false);
                hb[hnxt][pm] = (unsigned char)(pk & 0xff);
                Hout[((size_t)bat*LSEQ + tt)*512 + dir*256 + pm] = __float2bfloat16(h);
            }
        }
        // publish hb only (gx register-tracked, stores free-run)
        asm volatile("s_waitcnt lgkmcnt(0)" ::: "memory");
        __builtin_amdgcn_s_barrier();
        __builtin_amdgcn_sched_barrier(0);
        gc = gn; gn = gf2;
    }
}

// ================= bilinear body =================
__device__ __forceinline__ void bilinear_body(char* smem, const float* __restrict__ hidden,
        const int* __restrict__ pos, const float* __restrict__ Wb, const float* __restrict__ bb,
        float* __restrict__ pf, int idx){
    int c = idx & 127, b = idx >> 7;
    float (*fl)[516] = (float(*)[516])smem;
    float (*tl)[516] = (float(*)[516])(smem + 33024);
    int tid = threadIdx.x;
    for(int i=tid; i<2048; i+=512){
        int k = i>>7, d = (i&127)*4;
        int p = pos[b*KC + k];
        f32x4 v = *(const f32x4*)(hidden + ((size_t)b*LSEQ + p)*DDIM + d);
        fl[k][d]=v.x; fl[k][d+1]=v.y; fl[k][d+2]=v.z; fl[k][d+3]=v.w;
    }
    __syncthreads();
    int e = tid;
    float acc[16];
    #pragma unroll
    for(int k=0;k<16;k++) acc[k]=0.f;
    const float* wc = Wb + (size_t)c*512*512;
    for(int d=0; d<512; ++d){
        float wv = wc[(size_t)d*512 + e];
        #pragma unroll
        for(int k=0;k<16;k++) acc[k] += fl[k][d]*wv;
    }
    #pragma unroll
    for(int k=0;k<16;k++) tl[k][e] = acc[k];
    __syncthreads();
    if(tid < 256){
        int kq = tid>>4, mq = tid&15;
        const f32x4* tp = (const f32x4*)&tl[kq][0];
        const f32x4* fp = (const f32x4*)&fl[mq][0];
        float s = 0.f;
        #pragma unroll 8
        for(int e2=0;e2<128;e2++){ f32x4 a=tp[e2], v=fp[e2]; s += a.x*v.x + a.y*v.y + a.z*v.z + a.w*v.w; }
        pf[(((size_t)b*16+kq)*16+mq)*128 + c] = s + bb[c];
    }
}

// ================= cls + greedy body =================
__device__ __forceinline__ void clsgreedy_body(char* smem, const float* __restrict__ pf,
        const float* __restrict__ w1, const float* __restrict__ b1,
        const float* __restrict__ w2, const float* __restrict__ b2,
        const int* __restrict__ pos, float* __restrict__ prob, float* __restrict__ sel, int b){
    float (*sw1)[128] = (float(*)[128])smem;
    float* sw2 = (float*)(smem + 32768);
    float* sb1 = sw2 + 64;
    float* sp  = sb1 + 64;
    unsigned char* si = (unsigned char*)(sp + 120);
    unsigned char* sj = si + 120;
    int tid = threadIdx.x;
    for(int i=tid; i<8192; i+=512) sw1[i>>7][i&127] = w1[i];
    if(tid<64){ sw2[tid]=w2[tid]; sb1[tid]=b1[tid]; }
    if(tid==0){
        int idx=0;
        for(int i=0;i<16;i++) for(int j=i+1;j<16;j++){ si[idx]=(unsigned char)i; sj[idx]=(unsigned char)j; idx++; }
    }
    if(tid<256) sel[b*256+tid] = 0.f;
    __syncthreads();
    if(tid < 256){
        int k = tid>>4, m = tid&15;
        const f32x4* pp = (const f32x4*)(pf + (((size_t)b*16+k)*16+m)*128);
        f32x4 pr[32];
        #pragma unroll
        for(int i=0;i<32;i++) pr[i] = pp[i];
        float lg = b2[0];
        for(int n=0;n<64;n++){
            const f32x4* wr = (const f32x4*)&sw1[n][0];
            float a = sb1[n];
            #pragma unroll
            for(int i=0;i<32;i++){ f32x4 wv = wr[i]; a += pr[i].x*wv.x + pr[i].y*wv.y + pr[i].z*wv.z + pr[i].w*wv.w; }
            a = fmaxf(a, 0.f);
            lg += a*sw2[n];
        }
        float p = rcp_(1.f + ex2_(lg * -1.44269504f));
        int dk = pos[b*16+k]-pos[b*16+m]; if(dk<0) dk=-dk;
        if(dk<2) p *= 0.1f;
        prob[b*256 + k*16 + m] = p;
        if(k < m) sp[k*(31-k)/2 + (m-k-1)] = p;
    }
    __syncthreads();
    if(tid==0){
        bool done[120]; bool used[16];
        for(int i=0;i<120;i++) done[i]=false;
        for(int i=0;i<16;i++)  used[i]=false;
        for(int it=0; it<120; ++it){
            int bi=-1; float bp=-1e30f;
            for(int q=0;q<120;q++) if(!done[q] && sp[q]>bp){ bp=sp[q]; bi=q; }
            done[bi]=true;
            if(bp>0.5f && !used[si[bi]] && !used[sj[bi]]){
                used[si[bi]]=true; used[sj[bi]]=true;
                sel[b*256 + si[bi]*16 + sj[bi]] = 1.f;
            }
        }
    }
}

// ================= fused launches =================
__global__ __launch_bounds__(512) void k_fused1(const float* __restrict__ Whh, __hip_bfloat16* __restrict__ Gx,
        __hip_bfloat16* __restrict__ Hout, int* __restrict__ cnt,
        const __hip_bfloat16* __restrict__ hbf, const __hip_bfloat16* __restrict__ wihbf,
        const float* __restrict__ bias2,
        const float* __restrict__ hidden, const int* __restrict__ pos,
        const float* __restrict__ Wbil, const float* __restrict__ bbil, float* __restrict__ pf){
    __shared__ __attribute__((aligned(16))) char smem[98304];
    int bid = blockIdx.x;
    if(bid < 16){
        recur_body(smem, Whh, Gx, Hout, cnt, 0, bid>>1, bid&1);
    } else if(bid < 16 + 2048){
        gemm_body(smem, hbf, wihbf, bias2, Gx, cnt, bid - 16);
    } else {
        bilinear_body(smem, hidden, pos, Wbil, bbil, pf, bid - 2064);
    }
}

__global__ __launch_bounds__(512) void k_fused2(const float* __restrict__ Whh, __hip_bfloat16* __restrict__ Gx,
        __hip_bfloat16* __restrict__ Hout, int* __restrict__ cnt,
        const __hip_bfloat16* __restrict__ out1, const __hip_bfloat16* __restrict__ wihbf,
        const float* __restrict__ bias2,
        const float* __restrict__ pf, const float* __restrict__ w1, const float* __restrict__ b1,
        const float* __restrict__ w2, const float* __restrict__ b2, const int* __restrict__ pos,
        float* __restrict__ prob, float* __restrict__ sel){
    __shared__ __attribute__((aligned(16))) char smem[98304];
    int bid = blockIdx.x;
    if(bid < 16){
        recur_body(smem, Whh, Gx, Hout, cnt, 1, bid>>1, bid&1);
    } else if(bid < 16 + 2048){
        gemm_body(smem, out1, wihbf + (size_t)2048*512, bias2 + 2048, Gx, cnt, bid - 16);
    } else {
        clsgreedy_body(smem, pf, w1, b1, w2, b2, pos, prob, sel, bid - 2064);
    }
}

// ================= conv (ce computed in staging) + final fusion =================
// co split in halves; XCD-parity mapping keeps one 2.88MB wt-half L2-resident per XCD.
__global__ __launch_bounds__(256) void k_convce(const float* __restrict__ hs, const __hip_bfloat16* __restrict__ opt,
        const float* __restrict__ win, const float* __restrict__ cm, const float* __restrict__ dsb,
        const __hip_bfloat16* __restrict__ wt, const float* __restrict__ convb, float* __restrict__ outp){
    int xcd = blockIdx.x & 7;          // MI355X round-robin dispatch heuristic (perf-only)
    int j   = blockIdx.x >> 3;         // [0,64)
    int coH = xcd & 1;
    int tix = (xcd >> 1) * 64 + j;     // [0,256)
    int mt  = tix >> 3, b = tix & 7;
    __shared__ __hip_bfloat16 S[74][520];
    int tid = threadIdx.x;
    for(int i=tid; i<74*64; i+=256){
        int rq = i>>6, cc = (i&63)*8;
        int tok = mt*64 - 5 + rq;
        i32x4 o = (i32x4){0,0,0,0};
        if(tok>=0 && tok<LSEQ){
            size_t base = ((size_t)b*LSEQ + tok)*512 + cc;
            float wv = win[b*LSEQ+tok]*0.4f, cv = cm[b*LSEQ+tok];
            f32x4 h0 = *(const f32x4*)(hs + base);
            f32x4 h1 = *(const f32x4*)(hs + base + 4);
            unsigned long long u0 = *(const unsigned long long*)(opt + base);
            unsigned long long u1 = *(const unsigned long long*)(opt + base + 4);
            f32x4 d0 = *(const f32x4*)(dsb + cc);
            f32x4 d1 = *(const f32x4*)(dsb + cc + 4);
            float c0 = h0.x + wv*__uint_as_float((unsigned)(u0      & 0xffffull)<<16) + d0.x*cv;
            float c1 = h0.y + wv*__uint_as_float((unsigned)((u0>>16)& 0xffffull)<<16) + d0.y*cv;
            float c2 = h0.z + wv*__uint_as_float((unsigned)((u0>>32)& 0xffffull)<<16) + d0.z*cv;
            float c3 = h0.w + wv*__uint_as_float((unsigned)((u0>>48)& 0xffffull)<<16) + d0.w*cv;
            float c4 = h1.x + wv*__uint_as_float((unsigned)(u1      & 0xffffull)<<16) + d1.x*cv;
            float c5 = h1.y + wv*__uint_as_float((unsigned)((u1>>16)& 0xffffull)<<16) + d1.y*cv;
            float c6 = h1.z + wv*__uint_as_float((unsigned)((u1>>32)& 0xffffull)<<16) + d1.z*cv;
            float c7 = h1.w + wv*__uint_as_float((unsigned)((u1>>48)& 0xffffull)<<16) + d1.w*cv;
            o.x = pk2(c0,c1); o.y = pk2(c2,c3); o.z = pk2(c4,c5); o.w = pk2(c6,c7);
        }
        *(i32x4*)(&S[rq][cc]) = o;
    }
    __syncthreads();
    int w = tid>>6, lane = tid&63, lo = lane&15, hi = lane>>4;
    f32x4 acc[4][4];                    // [ms][s] — co slice = coH*256 + w*64 + s*16 + lo
    #pragma unroll
    for(int ms=0;ms<4;ms++){
        #pragma unroll
        for(int s=0;s<4;s++) acc[ms][s] = (f32x4){0.f,0.f,0.f,0.f};
    }
    asm volatile("s_nop 1" ::);
    for(int tap=0; tap<11; ++tap){
        const __hip_bfloat16* wtp = wt + (size_t)tap*262144 + (size_t)(coH*256 + w*64)*512;
        for(int kk=0; kk<512; kk+=32){
            i32x4 a[4];
            #pragma unroll
            for(int ms=0;ms<4;ms++) a[ms] = *(const i32x4*)(&S[ms*16 + lo + tap][kk + hi*8]);
            #pragma unroll
            for(int s=0;s<4;s++){
                i32x4 bq = *(const i32x4*)(wtp + (size_t)(s*16 + lo)*512 + kk + hi*8);
                #pragma unroll
                for(int ms=0;ms<4;ms++)
                    asm volatile("v_mfma_f32_16x16x32_bf16 %0, %1, %2, %0" : "+v"(acc[ms][s]) : "v"(a[ms]), "v"(bq));
            }
        }
    }
    asm volatile("s_nop 7\n\ts_nop 7" ::);
    #pragma unroll
    for(int s=0;s<4;s++){
        int co = coH*256 + w*64 + s*16 + lo;
        float cb = convb[co];
        #pragma unroll
        for(int ms=0;ms<4;ms++){
            #pragma unroll
            for(int rr=0; rr<4; ++rr){
                int row = ms*16 + hi*4 + rr;
                int tok = mt*64 + row;
                size_t gi = ((size_t)b*LSEQ + tok)*512 + co;
                float h   = hs[gi];
                float cef = __bfloat162float(S[row + 5][co]);
                outp[gi] = 0.5f*h + 0.3f*cef + 0.2f*(acc[ms][s][rr] + cb);
            }
        }
    }
}

// ================= launch =================
extern "C" void kernel_launch(void* const* d_in, const int* in_sizes, int n_in,
                              void* d_out, int out_size, void* d_ws, size_t ws_size,
                              hipStream_t stream)
{
    (void)in_sizes; (void)n_in; (void)out_size; (void)ws_size;
    const float* hidden = (const float*)d_in[0];
    const int*   aa     = (const int*)d_in[1];
    const float* Wbil   = (const float*)d_in[2];
    const float* bbil   = (const float*)d_in[3];
    const float* w1     = (const float*)d_in[4];
    const float* b1     = (const float*)d_in[5];
    const float* w2     = (const float*)d_in[6];
    const float* b2     = (const float*)d_in[7];
    const float* Wih    = (const float*)d_in[8];
    const float* Whh    = (const float*)d_in[9];
    const float* bih    = (const float*)d_in[10];
    const float* bhh    = (const float*)d_in[11];
    const float* convw  = (const float*)d_in[12];
    const float* convb  = (const float*)d_in[13];
    const float* dsb    = (const float*)d_in[14];

    float* outp = (float*)d_out;
    float* prob = outp + (size_t)NB*LSEQ*DDIM;
    float* sel  = prob + NB*KC*KC;

    char* p = (char*)d_ws;
    auto alloc = [&](size_t bytes)->char*{ char* r = p; p += (bytes + 255) & ~(size_t)255; return r; };
    __hip_bfloat16* gx    = (__hip_bfloat16*)alloc((size_t)16384*2048*2);
    __hip_bfloat16* hbf   = (__hip_bfloat16*)alloc((size_t)NB*LSEQ*DDIM*2);
    __hip_bfloat16* wihbf = (__hip_bfloat16*)alloc((size_t)2*2048*512*2);
    float*          bias2 = (float*)        alloc((size_t)2*2048*4);
    __hip_bfloat16* out1  = (__hip_bfloat16*)alloc((size_t)NB*LSEQ*DDIM*2);
    __hip_bfloat16* out2  = (__hip_bfloat16*)alloc((size_t)NB*LSEQ*DDIM*2);
    __hip_bfloat16* wtc   = (__hip_bfloat16*)alloc((size_t)11*512*512*2);
    float*          pf    = (float*)        alloc((size_t)NB*KC*KC*128*4);
    int*            pos   = (int*)          alloc((size_t)NB*KC*4);
    float*          cm    = (float*)        alloc((size_t)NB*LSEQ*4);
    float*          win   = (float*)        alloc((size_t)NB*LSEQ*4);
    int*            cnt1  = (int*)          alloc((size_t)512*4);
    int*            cnt2  = cnt1 + 128;

    // 1) prep: casts (wihbf/bias2 gate-interleaved), conv-w transpose, pos/cm/win, counters
    k_prep<<<6169, 256, 0, stream>>>(hidden, hbf, Wih, wihbf, bih, bhh, bias2, convw, wtc, aa, pos, cm, win, cnt1);
    // 2) recur L1 || gemm L1 (producer, counter-signaled) || bilinear
    k_fused1<<<16 + 2048 + 1024, 512, 0, stream>>>(Whh, gx, out1, cnt1, hbf, wihbf, bias2,
                                                   hidden, pos, Wbil, bbil, pf);
    // 3) recur L2 || gemm L2 || cls+greedy
    k_fused2<<<16 + 2048 + 8, 512, 0, stream>>>(Whh, gx, out2, cnt2, out1, wihbf, bias2,
                                                pf, w1, b1, w2, b2, pos, prob, sel);
    // 4) conv (+ce) + final fusion, co-split for wt L2 residency
    k_convce<<<512, 256, 0, stream>>>(hidden, out2, win, cm, dsb, wtc, convb, outp);
}